// Round 7
// baseline (2513.563 us; speedup 1.0000x reference)
//
#include <hip/hip_runtime.h>
#include <hip/hip_bf16.h>

typedef __bf16 bf16x8 __attribute__((ext_vector_type(8)));
typedef __bf16 bf16x4 __attribute__((ext_vector_type(4)));
typedef float  f32x4  __attribute__((ext_vector_type(4)));
typedef float  f32x16 __attribute__((ext_vector_type(16)));

#define B_    64
#define CIN   64
#define HIN   64
#define WIN   64
#define COUT  128
#define HO    62
#define WO    62
#define NPIX  (B_*HO*WO)        /* 246016 = 1922*128 exactly */
#define NITER 10                /* LDS rounds; +1 final matvec = 11 total */

// ---------------------------------------------------------------------------
// prep_w: build LDS-ready fragment images.
//  wtl: conv weights per c_out slice s: [s][tap][k4][khalf][m31] bf16x8 units
//       value = W_ff[o=32s+m31][c=k4*16+khalf*8+j][kh][kw]       (73728 el)
//  wrl: iterate -W_rec: [mt][kt][khalf][m31] bf16x8 units
//       value = -W_rec[o=32mt+m31][c=kt*16+khalf*8+j]            (16384 el)
// Total 90112 el = 352*256.
// ---------------------------------------------------------------------------
__global__ void prep_w_kernel(const float* __restrict__ wff,
                              const float* __restrict__ wrec,
                              __bf16* __restrict__ wtl,
                              __bf16* __restrict__ wrl) {
  int i = blockIdx.x * 256 + threadIdx.x;
  if (i < 73728) {
    int j = i & 7;
    int u = i >> 3;
    int m31 = u & 31, khalf = (u >> 5) & 1, k4 = (u >> 6) & 3;
    int st = u >> 8;
    int tap = st % 9, s = st / 9;
    int c = k4 * 16 + khalf * 8 + j;
    int o = s * 32 + m31;
    int kh = tap / 3, kw = tap % 3;
    wtl[i] = (__bf16)wff[((o * 64 + c) * 3 + kh) * 3 + kw];
  } else {
    int t = i - 73728;
    int j = t & 7;
    int u = t >> 3;
    int m31 = u & 31, khalf = (u >> 5) & 1, kt = (u >> 6) & 7, mt = u >> 9;
    int c = kt * 16 + khalf * 8 + j;
    int o = mt * 32 + m31;
    wrl[t] = (__bf16)(-wrec[o * 128 + c]);
  }
}

// ---------------------------------------------------------------------------
// prep_x: x NCHW fp32 -> bf16, layout [b][h][c>>3][w][c&7] (8KB per (b,h) row)
// ---------------------------------------------------------------------------
__global__ void prep_x_kernel(const float* __restrict__ x,
                              __bf16* __restrict__ xh) {
  __shared__ float t[64][65];
  int tid = threadIdx.x;
  int b = blockIdx.x >> 6;
  int h = blockIdx.x & 63;
#pragma unroll
  for (int it = 0; it < 16; ++it) {
    int c = it * 4 + (tid >> 6);
    int w = tid & 63;
    t[c][w] = x[(((size_t)(b * 64 + c)) * 64 + h) * 64 + w];
  }
  __syncthreads();
  size_t rowbase = (size_t)blockIdx.x * 4096;
#pragma unroll
  for (int it = 0; it < 16; ++it) {
    int j = it * 256 + tid;
    int c8  = j & 7;
    int w   = (j >> 3) & 63;
    int grp = j >> 9;
    xh[rowbase + j] = (__bf16)t[grp * 8 + c8][w];
  }
}

// ---------------------------------------------------------------------------
// conv v3: both MFMA operands from LDS (no persistent-reg weights — the
// allocator defeated that in R1-R6). Block = 2 output rows x 62 px x one
// 32-channel c_out slice. Grid (31, 64, 4). 4 waves x 32 px, single pass
// of 36 {A-read, B-read, MFMA 32x32x16}; acc = 16 regs only.
// ---------------------------------------------------------------------------
__global__ __launch_bounds__(256, 2) void conv_kernel(
    const __bf16* __restrict__ xh, const __bf16* __restrict__ wtl,
    float* __restrict__ u0) {
  __shared__ __align__(16) __bf16 xs[4 * 4096];       // 4 input rows, 32 KB
  __shared__ __align__(16) __bf16 ws[36 * 2 * 32 * 8]; // weight slice, 36 KB
  int tid  = threadIdx.x;
  int lane = tid & 63;
  int wv   = tid >> 6;
  int rg = blockIdx.x;                      // 0..30 : output rows 2rg, 2rg+1
  int b  = blockIdx.y;
  int s  = blockIdx.z;                      // c_out slice

  // stage 4 input rows (rg*2 .. rg*2+3), 32 chunks of 1KB
#pragma unroll
  for (int i = 0; i < 8; ++i) {
    int chunk = wv * 8 + i;                 // 0..31
    int row = chunk >> 3, part = chunk & 7;
    const __bf16* g = xh + ((size_t)(b * 64 + rg * 2 + row)) * 4096 + part * 512 + lane * 8;
    __bf16* l = xs + chunk * 512;
    __builtin_amdgcn_global_load_lds(
        (const __attribute__((address_space(1))) void*)g,
        (__attribute__((address_space(3))) void*)l, 16, 0, 0);
  }
  // stage weight slice: 36 chunks of 1KB
#pragma unroll
  for (int i = 0; i < 9; ++i) {
    int chunk = wv * 9 + i;                 // 0..35
    const __bf16* g = wtl + (size_t)s * 18432 + chunk * 512 + lane * 8;
    __bf16* l = ws + chunk * 512;
    __builtin_amdgcn_global_load_lds(
        (const __attribute__((address_space(1))) void*)g,
        (__attribute__((address_space(3))) void*)l, 16, 0, 0);
  }
  __syncthreads();

  int l31 = lane & 31;
  int khalf = lane >> 5;
  int px = wv * 32 + l31;                   // 0..127; valid < 124
  bool valid = px < 124;
  int px4 = valid ? px : 123;
  int r = px4 >= 62;
  int wcol = px4 - r * 62;

  f32x16 acc;
#pragma unroll
  for (int q = 0; q < 16; ++q) acc[q] = 0.f;

#pragma unroll
  for (int f = 0; f < 36; ++f) {            // f = tap*4 + k4
    int tap = f >> 2, k4 = f & 3;
    int kh = tap / 3, kw = tap % 3;
    bf16x8 A = *(const bf16x8*)&ws[((f * 2 + khalf) * 32 + l31) * 8];
    bf16x8 Bv = *(const bf16x8*)&xs[((r + kh) * 8 + k4 * 2 + khalf) * 512 + (wcol + kw) * 8];
    acc = __builtin_amdgcn_mfma_f32_32x32x16_bf16(A, Bv, acc, 0, 0, 0);
  }
  if (valid) {
    size_t pix = ((size_t)b * HO + rg * 2 + r) * WO + wcol;
    // C/D 32x32: col=lane&31(px), row=(reg&3)+8*(reg>>2)+4*khalf
    float* up = u0 + pix * COUT + s * 32 + khalf * 4;
#pragma unroll
    for (int g4 = 0; g4 < 4; ++g4) {
      f32x4 v;
#pragma unroll
      for (int q = 0; q < 4; ++q) v[q] = acc[g4 * 4 + q];
      *(f32x4*)&up[g4 * 8] = v;
    }
  }
}

// ---------------------------------------------------------------------------
// iterate v4: 11 undamped Picard matvecs on-chip. 256 thr = 4 waves; wave
// owns 32 px (32x32x16 shape), all 128 channels. -Wr frag image in LDS,
// re-read per matvec (kt index rotated by `it` to defeat LICM hoisting —
// the reg-persistent variants lost in R2-R6). No barriers in the loop:
// each wave reads/writes only its own 32 a_s rows.
// ---------------------------------------------------------------------------
__global__ __launch_bounds__(256, 2) void iterate_kernel(
    const float* __restrict__ u0, const __bf16* __restrict__ wrl,
    const float* __restrict__ thr, float* __restrict__ out) {
  __shared__ __align__(16) __bf16 a_s[128][136];      // 34816 B
  __shared__ __align__(16) __bf16 wr_s[16384];        // 32768 B
  int tid = threadIdx.x;
  int lane = tid & 63, wv = tid >> 6;
  int l31 = lane & 31, khalf = lane >> 5;
  int npx = wv * 32 + l31;                  // this lane's pixel row
  size_t p = (size_t)blockIdx.x * 128 + npx;
  int pb = (int)(p / (HO * WO));
  int pr = (int)(p % (HO * WO));

  // stage wr_s: 32 chunks of 1KB
#pragma unroll
  for (int i = 0; i < 8; ++i) {
    int chunk = wv * 8 + i;
    const __bf16* g = wrl + chunk * 512 + lane * 8;
    __bf16* l = wr_s + chunk * 512;
    __builtin_amdgcn_global_load_lds(
        (const __attribute__((address_space(1))) void*)g,
        (__attribute__((address_space(3))) void*)l, 16, 0, 0);
  }

  // u0 - thr in C-layout: ch = mt*32 + g4*8 + khalf*4 + q
  f32x16 u0f[4];
#pragma unroll
  for (int mt = 0; mt < 4; ++mt)
#pragma unroll
    for (int g4 = 0; g4 < 4; ++g4) {
      f32x4 uu = *(const f32x4*)&u0[p * COUT + mt * 32 + g4 * 8 + khalf * 4];
      f32x4 tt = *(const f32x4*)&thr[mt * 32 + g4 * 8 + khalf * 4];
#pragma unroll
      for (int q = 0; q < 4; ++q) u0f[mt][g4 * 4 + q] = uu[q] - tt[q];
    }

  // a_0 = relu(u0-thr) -> LDS
#pragma unroll
  for (int mt = 0; mt < 4; ++mt)
#pragma unroll
    for (int g4 = 0; g4 < 4; ++g4) {
      bf16x4 pk;
#pragma unroll
      for (int q = 0; q < 4; ++q) pk[q] = (__bf16)fmaxf(u0f[mt][g4 * 4 + q], 0.f);
      *(bf16x4*)&a_s[npx][mt * 32 + g4 * 8 + khalf * 4] = pk;
    }
  __syncthreads();                          // wr_s visible to all waves

#pragma unroll 1
  for (int it = 0; it < NITER; ++it) {
    bf16x8 Bf[8];
#pragma unroll
    for (int kt = 0; kt < 8; ++kt)
      Bf[kt] = *(const bf16x8*)&a_s[npx][kt * 16 + khalf * 8];
#pragma unroll
    for (int mt = 0; mt < 4; ++mt) {
      f32x16 acc = u0f[mt];
#pragma unroll
      for (int kt = 0; kt < 8; ++kt) {
        int kr = (kt + it) & 7;             // rotation defeats LICM hoist
        bf16x8 A = *(const bf16x8*)&wr_s[(((mt * 8 + kr) * 2 + khalf) * 32 + l31) * 8];
        acc = __builtin_amdgcn_mfma_f32_32x32x16_bf16(A, Bf[kr], acc, 0, 0, 0);
      }
#pragma unroll
      for (int g4 = 0; g4 < 4; ++g4) {
        bf16x4 pk;
#pragma unroll
        for (int q = 0; q < 4; ++q) pk[q] = (__bf16)fmaxf(acc[g4 * 4 + q], 0.f);
        *(bf16x4*)&a_s[npx][mt * 32 + g4 * 8 + khalf * 4] = pk;
      }
    }
  }
  // final matvec -> relu -> NCHW store
  {
    bf16x8 Bf[8];
#pragma unroll
    for (int kt = 0; kt < 8; ++kt)
      Bf[kt] = *(const bf16x8*)&a_s[npx][kt * 16 + khalf * 8];
#pragma unroll
    for (int mt = 0; mt < 4; ++mt) {
      f32x16 acc = u0f[mt];
#pragma unroll
      for (int kt = 0; kt < 8; ++kt) {
        int kr = (kt + NITER) & 7;
        bf16x8 A = *(const bf16x8*)&wr_s[(((mt * 8 + kr) * 2 + khalf) * 32 + l31) * 8];
        acc = __builtin_amdgcn_mfma_f32_32x32x16_bf16(A, Bf[kr], acc, 0, 0, 0);
      }
#pragma unroll
      for (int g4 = 0; g4 < 4; ++g4)
#pragma unroll
        for (int q = 0; q < 4; ++q) {
          int ch = mt * 32 + g4 * 8 + khalf * 4 + q;
          out[((size_t)pb * COUT + ch) * (HO * WO) + pr] = fmaxf(acc[g4 * 4 + q], 0.f);
        }
    }
  }
}

// ---------------------------------------------------------------------------
extern "C" void kernel_launch(void* const* d_in, const int* in_sizes, int n_in,
                              void* d_out, int out_size, void* d_ws, size_t ws_size,
                              hipStream_t stream) {
  const float* x    = (const float*)d_in[0];   // (64,64,64,64)
  const float* wff  = (const float*)d_in[1];   // (128,64,3,3)
  const float* wrec = (const float*)d_in[2];   // (128,128,1,1)
  const float* thr  = (const float*)d_in[3];   // (128,)
  float* out = (float*)d_out;                  // (64,128,62,62)

  char* ws = (char*)d_ws;
  size_t off = 0;
  float*  u0  = (float*)(ws + off);  off += (size_t)NPIX * COUT * 4;          // 126 MB
  __bf16* xh  = (__bf16*)(ws + off); off += (size_t)B_ * HIN * WIN * CIN * 2; // 33.6 MB
  __bf16* wtl = (__bf16*)(ws + off); off += 73728 * 2;                        // 144 KB
  __bf16* wrl = (__bf16*)(ws + off); off += 16384 * 2;                        // 32 KB

  prep_w_kernel<<<352, 256, 0, stream>>>(wff, wrec, wtl, wrl);
  prep_x_kernel<<<B_ * HIN, 256, 0, stream>>>(x, xh);
  conv_kernel<<<dim3(31, B_, 4), 256, 0, stream>>>(xh, wtl, u0);
  iterate_kernel<<<NPIX / 128, 256, 0, stream>>>(u0, wrl, thr, out);
}